// Round 11
// baseline (96.208 us; speedup 1.0000x reference)
//
#include <hip/hip_runtime.h>

#define BATCH 8192
#define DIM 1024
#define HEADS 8
#define HEAD_DIM 128
#define DSTATE 256

typedef __attribute__((ext_vector_type(8))) short short8v;   // 8 bf16 (4 VGPRs)
typedef __attribute__((ext_vector_type(4))) float f32x4;
typedef __attribute__((ext_vector_type(4))) unsigned short ushort4v;
typedef __attribute__((ext_vector_type(4))) unsigned int uint4v;

__device__ __forceinline__ unsigned short f2bf(float x) {
  unsigned int u = __builtin_bit_cast(unsigned int, x);
  unsigned int r = u + 0x7FFFu + ((u >> 16) & 1u);   // RNE
  return (unsigned short)(r >> 16);
}
__device__ __forceinline__ float bf2f(unsigned short h) {
  unsigned int u = ((unsigned int)h) << 16;
  return __builtin_bit_cast(float, u);
}

// async global->LDS: dest = uniform LDS base + lane*size; source is PER-LANE.
__device__ __forceinline__ void stage16f(const float* g, float* l) {
  __builtin_amdgcn_global_load_lds(
      (const __attribute__((address_space(1))) unsigned int*)g,
      (__attribute__((address_space(3))) unsigned int*)l, 16, 0, 0);
}
__device__ __forceinline__ void stage4u(const unsigned short* g, unsigned short* l) {
  __builtin_amdgcn_global_load_lds(
      (const __attribute__((address_space(1))) unsigned int*)g,
      (__attribute__((address_space(3))) unsigned int*)l, 4, 0, 0);
}

#define BARRIER() do { \
  asm volatile("s_waitcnt lgkmcnt(0)" ::: "memory"); \
  __builtin_amdgcn_s_barrier(); \
  asm volatile("" ::: "memory"); } while (0)

// Row permutation (within each head): stored row s <-> true n.
//   s = 32j + 16t + 4g + r   <->   n = 32j + 8g + 4t + r
// GEMM1's MFMA output (rows s) lands exactly in GEMM2's B-operand layout.

// ---------- prep: W1 (wn-folded, permuted) + A_bar + W2 + row scales + bf16 x_t ----------
__global__ __launch_bounds__(256) void prep(
    const float* __restrict__ logdt, const float* __restrict__ arelog,
    const float* __restrict__ aim,
    const float* __restrict__ Bre, const float* __restrict__ Bim,
    const float* __restrict__ Cre, const float* __restrict__ Cim,
    const float* __restrict__ xtg, const float* __restrict__ normw,
    unsigned short* __restrict__ w1re, unsigned short* __restrict__ w1im,
    unsigned short* __restrict__ w2re, unsigned short* __restrict__ w2mi,
    float* __restrict__ abr, float* __restrict__ abi,
    float* __restrict__ scale, unsigned short* __restrict__ xtb) {
  const int blk = blockIdx.x;
  if (blk < 1024) {
    const int i = blk * 256 + threadIdx.x;           // h*32768 + s*128 + p
    const int p = i & 127, s = (i >> 7) & 255, h = i >> 15;
    const int kk = s >> 4, u = s & 15;
    const int n = ((kk >> 1) << 5) + ((u >> 2) & 3) * 8 + (kk & 1) * 4 + (u & 3);
    const int hn = h * 256 + n;
    const float ld = logdt[hn];
    const float dt = log1pf(expf(ld));               // softplus
    const float Ar = -expf(arelog[hn]);
    const float Ai = aim[hn];
    const float e = expf(dt * Ar), th = dt * Ai;
    const float Abr = e * cosf(th), Abi = e * sinf(th);
    if (p == 0) { abr[h * 256 + s] = Abr; abi[h * 256 + s] = Abi; }
    const float den = Ar * Ar + Ai * Ai;
    const float br_ = Abr - 1.0f;
    const float cr = (br_ * Ar + Abi * Ai) / den;
    const float ci = (Abi * Ar - br_ * Ai) / den;
    const int src = hn * 128 + p;
    const float wb = normw[h * 128 + p];             // fold norm weight into W1
    const float bre = Bre[src], bim = Bim[src];
    w1re[i] = f2bf((cr * bre - ci * bim) * wb);
    w1im[i] = f2bf((cr * bim + ci * bre) * wb);
  } else if (blk < 2048) {
    const int i = (blk - 1024) * 256 + threadIdx.x;  // 262144 = H*P*N
    w2re[i] = f2bf(Cre[i]);
    w2mi[i] = f2bf(-Cim[i]);
  } else {
    const int wid = threadIdx.x >> 6, lane = threadIdx.x & 63;
    const int row = (blk - 2048) * 4 + wid;
    const float* xr = xtg + (size_t)row * DIM;
    unsigned short* xo = xtb + (size_t)row * DIM;
    float ssq = 0.f;
    #pragma unroll
    for (int c = 0; c < 4; ++c) {
      const f32x4 v = *(const f32x4*)(xr + c * 256 + lane * 4);
      ssq += v[0]*v[0] + v[1]*v[1] + v[2]*v[2] + v[3]*v[3];
      ushort4v o;
      o[0] = f2bf(v[0]); o[1] = f2bf(v[1]); o[2] = f2bf(v[2]); o[3] = f2bf(v[3]);
      *(ushort4v*)(xo + c * 256 + lane * 4) = o;
    }
    #pragma unroll
    for (int m = 1; m < 64; m <<= 1) ssq += __shfl_xor(ssq, m, 64);
    if (lane == 0) scale[row] = rsqrtf(ssq * (1.0f / DIM) + 1e-4f);
  }
}

// ---------- main: persistent block, reg weights, 4-buf single-barrier pipeline ----------
// Grid: 256 blocks = 32 row-groups x 8 heads (1 block/CU), 512 threads = 8 waves.
// Block: 256 rows x 1 head = 16 tiles. Wave w: GEMM1 n-window j=w, GEMM2 p-tile
// [16w,16w+16). One barrier per tile; phase2 deferred one tile:
//   iter t: vmcnt(N) -> BARRIER -> STAGE(t+2) -> sched_fence ->
//           PHASE2(t-1) [GEMM2-from-Sb + nt ns/out stores] || PHASE1(t).
// 4 LDS buffers: tiles t-1 (phase2), t (phase1), t+1, t+2 (staged/inflight).
__global__ __launch_bounds__(512, 2) void s5_main(
    const unsigned short* __restrict__ w1re, const unsigned short* __restrict__ w1im,
    const unsigned short* __restrict__ w2re, const unsigned short* __restrict__ w2mi,
    const float* __restrict__ abrp, const float* __restrict__ abip,
    const float* __restrict__ scale, const unsigned short* __restrict__ xtb,
    const float* __restrict__ sre, const float* __restrict__ sim,
    const float* __restrict__ dvec, const float* __restrict__ normw,
    float* __restrict__ out, float* __restrict__ nsre, float* __restrict__ nsim) {
  __shared__ float Sb[4][2][16][256];                // 128 KB state/ns tiles
  __shared__ unsigned short xbL[4][16][128];         // 16 KB bf16 x_t tiles (swizzled)
  __shared__ float scL[256];                         // 1 KB row scales
  const int tid = threadIdx.x;
  const int w = tid >> 6, lane = tid & 63;
  const int g = lane >> 4, bl = lane & 15;
  const int h = blockIdx.x & 7;
  const int blkrow = (blockIdx.x >> 3) * 256;

  // ---- persistent weights -> registers (once per block) ----
  short8v w1r[2][4], w1i[2][4];
  #pragma unroll
  for (int t = 0; t < 2; ++t) {
    const int kk = 2 * w + t;
    const unsigned short* pr = w1re + ((size_t)(h * DSTATE + kk * 16 + bl)) * HEAD_DIM + g * 8;
    const unsigned short* pi = w1im + ((size_t)(h * DSTATE + kk * 16 + bl)) * HEAD_DIM + g * 8;
    #pragma unroll
    for (int ks = 0; ks < 4; ++ks) {
      w1r[t][ks] = *(const short8v*)(pr + ks * 32);
      w1i[t][ks] = *(const short8v*)(pi + ks * 32);
    }
  }
  short8v w2r[8], w2i[8];
  {
    const unsigned short* qr = w2re + ((size_t)(h * HEAD_DIM + w * 16 + bl)) * DSTATE + g * 8;
    const unsigned short* qi = w2mi + ((size_t)(h * HEAD_DIM + w * 16 + bl)) * DSTATE + g * 8;
    #pragma unroll
    for (int j = 0; j < 8; ++j) {
      w2r[j] = *(const short8v*)(qr + j * 32);
      w2i[j] = *(const short8v*)(qi + j * 32);
    }
  }
  f32x4 Arh[2], Aih[2];
  #pragma unroll
  for (int t = 0; t < 2; ++t) {
    Arh[t] = *(const f32x4*)(abrp + h * DSTATE + (2 * w + t) * 16 + g * 4);
    Aih[t] = *(const f32x4*)(abip + h * DSTATE + (2 * w + t) * 16 + g * 4);
  }
  f32x4 d4;                                          // D * norm_weight (folded)
  {
    const int col = h * HEAD_DIM + w * 16 + g * 4;
    const f32x4 dv = *(const f32x4*)(dvec + col);
    const f32x4 nv = *(const f32x4*)(normw + col);
    #pragma unroll
    for (int r = 0; r < 4; ++r) d4[r] = dv[r] * nv[r];
  }

  // ---- STAGE tile t into buffer b: 6 uniform vm ops per wave ----
  auto STAGE = [&](int t, int b) {
    const int gr0 = blkrow + t * 16;
    #pragma unroll
    for (int i = 0; i < 2; ++i) {
      const int row = 2 * w + i;
      const size_t rb = ((size_t)(gr0 + row) * HEADS + h) * DSTATE;
      const int soff = (lane ^ (row & 7)) * 4;       // pre-swizzled source chunk
      stage16f(sre + rb + soff, &Sb[b][0][row][0]);
      stage16f(sim + rb + soff, &Sb[b][1][row][0]);
    }
    #pragma unroll
    for (int i = 0; i < 2; ++i) {
      const int row = 2 * w + i;                     // one 256B row per instr
      const unsigned short* src = xtb + (size_t)(gr0 + row) * DIM + h * HEAD_DIM
          + (((lane >> 2) ^ (row & 7)) << 3) + ((lane & 3) << 1);
      stage4u(src, &xbL[b][row][0]);
    }
  };

  // ---- PHASE1(t): x_hat frags, GEMM1 + recurrence, ns in-place in Sb ----
  auto PHASE1 = [&](int t) {
    const int b = t & 3;
    const float scl = scL[t * 16 + bl];
    short8v xf[4];
    #pragma unroll
    for (int ks = 0; ks < 4; ++ks) {
      const int ch = (ks * 4 + g) ^ (bl & 7);
      uint4v u = *(const uint4v*)&xbL[b][bl][ch * 8];
      uint4v o;
      #pragma unroll
      for (int q = 0; q < 4; ++q) {
        const float lo = bf2f((unsigned short)(u[q] & 0xffffu)) * scl;
        const float hi = bf2f((unsigned short)(u[q] >> 16)) * scl;
        o[q] = (unsigned)f2bf(lo) | ((unsigned)f2bf(hi) << 16);
      }
      xf[ks] = __builtin_bit_cast(short8v, o);
    }
    #pragma unroll
    for (int tt = 0; tt < 2; ++tt) {
      f32x4 dr = {0.f,0.f,0.f,0.f};
      f32x4 di = {0.f,0.f,0.f,0.f};
      #pragma unroll
      for (int ks = 0; ks < 4; ++ks)
        dr = __builtin_amdgcn_mfma_f32_16x16x32_bf16(w1r[tt][ks], xf[ks], dr, 0, 0, 0);
      #pragma unroll
      for (int ks = 0; ks < 4; ++ks)
        di = __builtin_amdgcn_mfma_f32_16x16x32_bf16(w1i[tt][ks], xf[ks], di, 0, 0, 0);
      const int c = (((8 * w + 2 * g + tt) ^ (bl & 7)) << 2);
      const f32x4 s_r = *(const f32x4*)&Sb[b][0][bl][c];
      const f32x4 s_i = *(const f32x4*)&Sb[b][1][bl][c];
      f32x4 nr, ni;
      #pragma unroll
      for (int r = 0; r < 4; ++r) {
        nr[r] = fmaf(Arh[tt][r], s_r[r], fmaf(-Aih[tt][r], s_i[r], dr[r]));
        ni[r] = fmaf(Arh[tt][r], s_i[r], fmaf(Aih[tt][r], s_r[r], di[r]));
      }
      *(f32x4*)&Sb[b][0][bl][c] = nr;
      *(f32x4*)&Sb[b][1][bl][c] = ni;
    }
  };

  // ---- PHASE2(t): nt ns store-out, GEMM2 from Sb, epilogue (5 vm stores/wave) ----
  auto PHASE2 = [&](int t) {
    const int b = t & 3;
    #pragma unroll
    for (int i = 0; i < 2; ++i) {
      const int row = 2 * w + i;
      const size_t rb = ((size_t)(blkrow + t * 16 + row) * HEADS + h) * DSTATE;
      const int gc = (lane ^ (row & 7)) * 4;
      const f32x4 vr = *(const f32x4*)&Sb[b][0][row][lane * 4];
      const f32x4 vi = *(const f32x4*)&Sb[b][1][row][lane * 4];
      __builtin_nontemporal_store(vr, (f32x4*)(nsre + rb + gc));
      __builtin_nontemporal_store(vi, (f32x4*)(nsim + rb + gc));
    }
    f32x4 a2 = {0.f,0.f,0.f,0.f};
    #pragma unroll
    for (int j = 0; j < 8; ++j) {
      const int c0 = (((8 * j + 2 * g)     ^ (bl & 7)) << 2);
      const int c1 = (((8 * j + 2 * g + 1) ^ (bl & 7)) << 2);
      const f32x4 r0 = *(const f32x4*)&Sb[b][0][bl][c0];
      const f32x4 r1 = *(const f32x4*)&Sb[b][0][bl][c1];
      const f32x4 i0 = *(const f32x4*)&Sb[b][1][bl][c0];
      const f32x4 i1 = *(const f32x4*)&Sb[b][1][bl][c1];
      uint4v ur, ui;
      ur[0] = (unsigned)f2bf(r0[0]) | ((unsigned)f2bf(r0[1]) << 16);
      ur[1] = (unsigned)f2bf(r0[2]) | ((unsigned)f2bf(r0[3]) << 16);
      ur[2] = (unsigned)f2bf(r1[0]) | ((unsigned)f2bf(r1[1]) << 16);
      ur[3] = (unsigned)f2bf(r1[2]) | ((unsigned)f2bf(r1[3]) << 16);
      ui[0] = (unsigned)f2bf(i0[0]) | ((unsigned)f2bf(i0[1]) << 16);
      ui[1] = (unsigned)f2bf(i0[2]) | ((unsigned)f2bf(i0[3]) << 16);
      ui[2] = (unsigned)f2bf(i1[0]) | ((unsigned)f2bf(i1[1]) << 16);
      ui[3] = (unsigned)f2bf(i1[2]) | ((unsigned)f2bf(i1[3]) << 16);
      const short8v pbr = __builtin_bit_cast(short8v, ur);
      const short8v pbi = __builtin_bit_cast(short8v, ui);
      a2 = __builtin_amdgcn_mfma_f32_16x16x32_bf16(w2r[j], pbr, a2, 0, 0, 0);
      a2 = __builtin_amdgcn_mfma_f32_16x16x32_bf16(w2i[j], pbi, a2, 0, 0, 0);
    }
    const float scl = scL[t * 16 + bl];
    const int col = h * HEAD_DIM + w * 16 + g * 4;
    const size_t o = (size_t)(blkrow + t * 16 + bl) * DIM + col;
    const unsigned short* xp =
        &xbL[b][bl][((((2 * w) + (g >> 1)) ^ (bl & 7)) << 3) + ((g & 1) << 2)];
    f32x4 ro;
    #pragma unroll
    for (int r = 0; r < 4; ++r) {
      const float xr = bf2f(xp[r]);
      ro[r] = xr * (1.0f + d4[r] * scl) + 2.0f * a2[r];
    }
    __builtin_nontemporal_store(ro, (f32x4*)(out + o));
  };

  // ---- prologue ----
  if (w == 0) stage16f(scale + blkrow + lane * 4, &scL[0]);   // 256 scales, 1 instr
  STAGE(0, 0);
  STAGE(1, 1);
  asm volatile("s_waitcnt vmcnt(6)" ::: "memory");   // scale + stage(0) retired

  for (int t = 0; t < 16; ++t) {
    if (t == 1)                asm volatile("s_waitcnt vmcnt(6)"  ::: "memory");
    else if (t == 2)           asm volatile("s_waitcnt vmcnt(11)" ::: "memory");
    else if (t >= 3 && t <= 14) asm volatile("s_waitcnt vmcnt(16)" ::: "memory");
    else if (t == 15)          asm volatile("s_waitcnt vmcnt(10)" ::: "memory");
    BARRIER();                                       // stage(t) visible to all
    if (t + 2 < 16) STAGE(t + 2, (t + 2) & 3);
    __builtin_amdgcn_sched_barrier(0);               // pin stage-before-stores order
    if (t > 0) PHASE2(t - 1);
    PHASE1(t);
  }
  BARRIER();
  PHASE2(15);
}

extern "C" void kernel_launch(void* const* d_in, const int* in_sizes, int n_in,
                              void* d_out, int out_size, void* d_ws, size_t ws_size,
                              hipStream_t stream) {
  const float* x_t      = (const float*)d_in[0];
  const float* state_re = (const float*)d_in[1];
  const float* state_im = (const float*)d_in[2];
  const float* norm_w   = (const float*)d_in[3];
  const float* A_re_log = (const float*)d_in[4];
  const float* A_im     = (const float*)d_in[5];
  const float* B_re     = (const float*)d_in[6];
  const float* B_im     = (const float*)d_in[7];
  const float* C_re     = (const float*)d_in[8];
  const float* C_im     = (const float*)d_in[9];
  const float* Dv       = (const float*)d_in[10];
  const float* log_dt   = (const float*)d_in[11];

  float* out   = (float*)d_out;
  float* ns_re = out + (size_t)BATCH * DIM;
  float* ns_im = ns_re + (size_t)BATCH * HEADS * DSTATE;

  char* ws = (char*)d_ws;
  unsigned short* w1re = (unsigned short*)ws;                       // 512 KB each
  unsigned short* w1im = w1re + 262144;
  unsigned short* w2re = w1im + 262144;
  unsigned short* w2mi = w2re + 262144;
  float* abr   = (float*)(ws + 4 * 524288);
  float* abi   = abr + 2048;
  float* scale = abi + 2048;                                        // 8192 f32
  unsigned short* xtb = (unsigned short*)(scale + 8192);            // 16.8 MB bf16 x_t

  prep<<<4096, 256, 0, stream>>>(log_dt, A_re_log, A_im, B_re, B_im, C_re, C_im,
                                 x_t, norm_w, w1re, w1im, w2re, w2mi,
                                 abr, abi, scale, xtb);
  s5_main<<<256, 512, 0, stream>>>(w1re, w1im, w2re, w2mi, abr, abi, scale, xtb,
                                   state_re, state_im, Dv, norm_w,
                                   out, ns_re, ns_im);
}

// Round 12
// 91.155 us; speedup vs baseline: 1.0554x; 1.0554x over previous
//
#include <hip/hip_runtime.h>

#define BATCH 8192
#define DIM 1024
#define HEADS 8
#define HEAD_DIM 128
#define DSTATE 256

typedef __attribute__((ext_vector_type(8))) short short8v;   // 8 bf16 (4 VGPRs)
typedef __attribute__((ext_vector_type(4))) float f32x4;
typedef __attribute__((ext_vector_type(4))) unsigned short ushort4v;
typedef __attribute__((ext_vector_type(4))) unsigned int uint4v;

__device__ __forceinline__ unsigned short f2bf(float x) {
  unsigned int u = __builtin_bit_cast(unsigned int, x);
  unsigned int r = u + 0x7FFFu + ((u >> 16) & 1u);   // RNE
  return (unsigned short)(r >> 16);
}
__device__ __forceinline__ float bf2f(unsigned short h) {
  unsigned int u = ((unsigned int)h) << 16;
  return __builtin_bit_cast(float, u);
}

// async global->LDS: dest = uniform LDS base + lane*size; source is PER-LANE.
__device__ __forceinline__ void stage16f(const float* g, float* l) {
  __builtin_amdgcn_global_load_lds(
      (const __attribute__((address_space(1))) unsigned int*)g,
      (__attribute__((address_space(3))) unsigned int*)l, 16, 0, 0);
}
__device__ __forceinline__ void stage4u(const unsigned short* g, unsigned short* l) {
  __builtin_amdgcn_global_load_lds(
      (const __attribute__((address_space(1))) unsigned int*)g,
      (__attribute__((address_space(3))) unsigned int*)l, 4, 0, 0);
}

#define BARRIER() do { \
  asm volatile("s_waitcnt lgkmcnt(0)" ::: "memory"); \
  __builtin_amdgcn_s_barrier(); \
  asm volatile("" ::: "memory"); } while (0)

// Row permutation (within each head): stored row s <-> true n.
//   s = 32j + 16t + 4g + r   <->   n = 32j + 8g + 4t + r
// GEMM1's MFMA output (rows s) lands exactly in GEMM2's B-operand layout.

// ---------- prep: W1 (wn-folded, permuted) + A_bar + W2 + row scales + bf16 x_t ----------
__global__ __launch_bounds__(256) void prep(
    const float* __restrict__ logdt, const float* __restrict__ arelog,
    const float* __restrict__ aim,
    const float* __restrict__ Bre, const float* __restrict__ Bim,
    const float* __restrict__ Cre, const float* __restrict__ Cim,
    const float* __restrict__ xtg, const float* __restrict__ normw,
    unsigned short* __restrict__ w1re, unsigned short* __restrict__ w1im,
    unsigned short* __restrict__ w2re, unsigned short* __restrict__ w2mi,
    float* __restrict__ abr, float* __restrict__ abi,
    float* __restrict__ scale, unsigned short* __restrict__ xtb) {
  const int blk = blockIdx.x;
  if (blk < 1024) {
    const int i = blk * 256 + threadIdx.x;           // h*32768 + s*128 + p
    const int p = i & 127, s = (i >> 7) & 255, h = i >> 15;
    const int kk = s >> 4, u = s & 15;
    const int n = ((kk >> 1) << 5) + ((u >> 2) & 3) * 8 + (kk & 1) * 4 + (u & 3);
    const int hn = h * 256 + n;
    const float ld = logdt[hn];
    const float dt = log1pf(expf(ld));               // softplus
    const float Ar = -expf(arelog[hn]);
    const float Ai = aim[hn];
    const float e = expf(dt * Ar), th = dt * Ai;
    const float Abr = e * cosf(th), Abi = e * sinf(th);
    if (p == 0) { abr[h * 256 + s] = Abr; abi[h * 256 + s] = Abi; }
    const float den = Ar * Ar + Ai * Ai;
    const float br_ = Abr - 1.0f;
    const float cr = (br_ * Ar + Abi * Ai) / den;
    const float ci = (Abi * Ar - br_ * Ai) / den;
    const int src = hn * 128 + p;
    const float wb = normw[h * 128 + p];             // fold norm weight into W1
    const float bre = Bre[src], bim = Bim[src];
    w1re[i] = f2bf((cr * bre - ci * bim) * wb);
    w1im[i] = f2bf((cr * bim + ci * bre) * wb);
  } else if (blk < 2048) {
    const int i = (blk - 1024) * 256 + threadIdx.x;  // 262144 = H*P*N
    w2re[i] = f2bf(Cre[i]);
    w2mi[i] = f2bf(-Cim[i]);
  } else {
    const int wid = threadIdx.x >> 6, lane = threadIdx.x & 63;
    const int row = (blk - 2048) * 4 + wid;
    const float* xr = xtg + (size_t)row * DIM;
    unsigned short* xo = xtb + (size_t)row * DIM;
    float ssq = 0.f;
    #pragma unroll
    for (int c = 0; c < 4; ++c) {
      const f32x4 v = *(const f32x4*)(xr + c * 256 + lane * 4);
      ssq += v[0]*v[0] + v[1]*v[1] + v[2]*v[2] + v[3]*v[3];
      ushort4v o;
      o[0] = f2bf(v[0]); o[1] = f2bf(v[1]); o[2] = f2bf(v[2]); o[3] = f2bf(v[3]);
      *(ushort4v*)(xo + c * 256 + lane * 4) = o;
    }
    #pragma unroll
    for (int m = 1; m < 64; m <<= 1) ssq += __shfl_xor(ssq, m, 64);
    if (lane == 0) scale[row] = rsqrtf(ssq * (1.0f / DIM) + 1e-4f);
  }
}

// ---------- main: persistent block, reg weights, 3-buf 2-deep pipeline ----------
// Grid: 256 blocks = 32 row-groups x 8 heads (1 block/CU), 512 threads = 8 waves.
// Wave w: GEMM1 n-window j=w (+ direct reg->global ns store via shfl fixup),
// GEMM2 p-tile [16w,16w+16). Iter t: vmcnt(N) -> BARRIER -> STAGE(t+2) ->
// PHASE1(t) [GEMM1+recur+ns-stores+pf] -> BARRIER -> PHASE2(t) [GEMM2+out].
// Sb is read-only state (no ns writeback) -> short phase2, stores spread early.
__global__ __launch_bounds__(512, 2) void s5_main(
    const unsigned short* __restrict__ w1re, const unsigned short* __restrict__ w1im,
    const unsigned short* __restrict__ w2re, const unsigned short* __restrict__ w2mi,
    const float* __restrict__ abrp, const float* __restrict__ abip,
    const float* __restrict__ scale, const unsigned short* __restrict__ xtb,
    const float* __restrict__ sre, const float* __restrict__ sim,
    const float* __restrict__ dvec, const float* __restrict__ normw,
    float* __restrict__ out, float* __restrict__ nsre, float* __restrict__ nsim) {
  __shared__ float Sb[3][2][16][256];                // 96 KB state tiles (read-only)
  __shared__ unsigned short xbL[3][16][128];         // 12 KB bf16 x_t tiles (swizzled)
  __shared__ unsigned short pf[2][8][64][8];         // 16 KB P exchange
  __shared__ float scL[256];                         // 1 KB row scales
  const int tid = threadIdx.x;
  const int w = tid >> 6, lane = tid & 63;
  const int g = lane >> 4, bl = lane & 15;
  const int h = blockIdx.x & 7;
  const int blkrow = (blockIdx.x >> 3) * 256;

  // ---- persistent weights -> registers (once per block) ----
  short8v w1r[2][4], w1i[2][4];
  #pragma unroll
  for (int t = 0; t < 2; ++t) {
    const int kk = 2 * w + t;
    const unsigned short* pr = w1re + ((size_t)(h * DSTATE + kk * 16 + bl)) * HEAD_DIM + g * 8;
    const unsigned short* pi = w1im + ((size_t)(h * DSTATE + kk * 16 + bl)) * HEAD_DIM + g * 8;
    #pragma unroll
    for (int ks = 0; ks < 4; ++ks) {
      w1r[t][ks] = *(const short8v*)(pr + ks * 32);
      w1i[t][ks] = *(const short8v*)(pi + ks * 32);
    }
  }
  short8v w2r[8], w2i[8];
  {
    const unsigned short* qr = w2re + ((size_t)(h * HEAD_DIM + w * 16 + bl)) * DSTATE + g * 8;
    const unsigned short* qi = w2mi + ((size_t)(h * HEAD_DIM + w * 16 + bl)) * DSTATE + g * 8;
    #pragma unroll
    for (int j = 0; j < 8; ++j) {
      w2r[j] = *(const short8v*)(qr + j * 32);
      w2i[j] = *(const short8v*)(qi + j * 32);
    }
  }
  f32x4 Arh[2], Aih[2];
  #pragma unroll
  for (int t = 0; t < 2; ++t) {
    Arh[t] = *(const f32x4*)(abrp + h * DSTATE + (2 * w + t) * 16 + g * 4);
    Aih[t] = *(const f32x4*)(abip + h * DSTATE + (2 * w + t) * 16 + g * 4);
  }
  f32x4 d4;                                          // D * norm_weight (folded)
  {
    const int col = h * HEAD_DIM + w * 16 + g * 4;
    const f32x4 dv = *(const f32x4*)(dvec + col);
    const f32x4 nv = *(const f32x4*)(normw + col);
    #pragma unroll
    for (int r = 0; r < 4; ++r) d4[r] = dv[r] * nv[r];
  }
  const int srcA = ((g >> 1) << 4) + bl;             // shfl sources, ns store fixup
  const int srcB = (((g >> 1) + 2) << 4) + bl;

  // ---- STAGE tile t into buffer b: 6 uniform vm ops per wave (x_t ops LAST) ----
  auto STAGE = [&](int t, int b) {
    const int gr0 = blkrow + t * 16;
    #pragma unroll
    for (int i = 0; i < 2; ++i) {
      const int row = 2 * w + i;
      const size_t rb = ((size_t)(gr0 + row) * HEADS + h) * DSTATE;
      const int soff = (lane ^ (row & 7)) * 4;       // pre-swizzled source chunk
      stage16f(sre + rb + soff, &Sb[b][0][row][0]);
      stage16f(sim + rb + soff, &Sb[b][1][row][0]);
    }
    #pragma unroll
    for (int i = 0; i < 2; ++i) {
      const int row = 2 * w + i;                     // one 256B row per instr
      const unsigned short* src = xtb + (size_t)(gr0 + row) * DIM + h * HEAD_DIM
          + (((lane >> 2) ^ (row & 7)) << 3) + ((lane & 3) << 1);
      stage4u(src, &xbL[b][row][0]);
    }
  };

  // ---- PHASE1(t): x_hat, GEMM1, recurrence, pf pack, shfl-fixup ns stores ----
  auto PHASE1 = [&](int t) {
    const int b = t % 3;
    const float scl = scL[t * 16 + bl];
    short8v xf[4];
    #pragma unroll
    for (int ks = 0; ks < 4; ++ks) {
      const int ch = (ks * 4 + g) ^ (bl & 7);
      uint4v u = *(const uint4v*)&xbL[b][bl][ch * 8];
      uint4v o;
      #pragma unroll
      for (int q = 0; q < 4; ++q) {
        const float lo = bf2f((unsigned short)(u[q] & 0xffffu)) * scl;
        const float hi = bf2f((unsigned short)(u[q] >> 16)) * scl;
        o[q] = (unsigned)f2bf(lo) | ((unsigned)f2bf(hi) << 16);
      }
      xf[ks] = __builtin_bit_cast(short8v, o);
    }
    f32x4 nre[2], nim[2];
    unsigned pr0 = 0, pr1 = 0, pi0 = 0, pi1 = 0;
    #pragma unroll
    for (int tt = 0; tt < 2; ++tt) {
      f32x4 dr = {0.f,0.f,0.f,0.f};
      f32x4 di = {0.f,0.f,0.f,0.f};
      #pragma unroll
      for (int ks = 0; ks < 4; ++ks)
        dr = __builtin_amdgcn_mfma_f32_16x16x32_bf16(w1r[tt][ks], xf[ks], dr, 0, 0, 0);
      #pragma unroll
      for (int ks = 0; ks < 4; ++ks)
        di = __builtin_amdgcn_mfma_f32_16x16x32_bf16(w1i[tt][ks], xf[ks], di, 0, 0, 0);
      const int c = (((8 * w + 2 * g + tt) ^ (bl & 7)) << 2);
      const f32x4 s_r = *(const f32x4*)&Sb[b][0][bl][c];
      const f32x4 s_i = *(const f32x4*)&Sb[b][1][bl][c];
      f32x4 nr, ni;
      #pragma unroll
      for (int r = 0; r < 4; ++r) {
        nr[r] = fmaf(Arh[tt][r], s_r[r], fmaf(-Aih[tt][r], s_i[r], dr[r]));
        ni[r] = fmaf(Arh[tt][r], s_i[r], fmaf(Aih[tt][r], s_r[r], di[r]));
      }
      nre[tt] = nr; nim[tt] = ni;
      unsigned lo  = (unsigned)f2bf(nr[0]) | ((unsigned)f2bf(nr[1]) << 16);
      unsigned hi  = (unsigned)f2bf(nr[2]) | ((unsigned)f2bf(nr[3]) << 16);
      unsigned lo2 = (unsigned)f2bf(ni[0]) | ((unsigned)f2bf(ni[1]) << 16);
      unsigned hi2 = (unsigned)f2bf(ni[2]) | ((unsigned)f2bf(ni[3]) << 16);
      if (tt == 0) { pr0 = lo; pr1 = hi; pi0 = lo2; pi1 = hi2; }
      else {
        uint4v urv; urv[0] = pr0; urv[1] = pr1; urv[2] = lo;  urv[3] = hi;
        uint4v uiv; uiv[0] = pi0; uiv[1] = pi1; uiv[2] = lo2; uiv[3] = hi2;
        *(short8v*)&pf[0][w][lane][0] = __builtin_bit_cast(short8v, urv);
        *(short8v*)&pf[1][w][lane][0] = __builtin_bit_cast(short8v, uiv);
      }
    }
    // shfl fix-up -> per-instruction 64B-contiguous-per-row ns stores (amp-free)
    f32x4 v1r, v2r, v1i, v2i;
    #pragma unroll
    for (int e = 0; e < 4; ++e) {
      float a1 = __shfl(nre[0][e], srcA, 64);
      float b1 = __shfl(nre[1][e], srcA, 64);
      v1r[e] = (g & 1) ? b1 : a1;
      float a2 = __shfl(nre[0][e], srcB, 64);
      float b2 = __shfl(nre[1][e], srcB, 64);
      v2r[e] = (g & 1) ? b2 : a2;
      float c1 = __shfl(nim[0][e], srcA, 64);
      float d1 = __shfl(nim[1][e], srcA, 64);
      v1i[e] = (g & 1) ? d1 : c1;
      float c2 = __shfl(nim[0][e], srcB, 64);
      float d2 = __shfl(nim[1][e], srcB, 64);
      v2i[e] = (g & 1) ? d2 : c2;
    }
    const size_t no = ((size_t)(blkrow + t * 16 + bl) * HEADS + h) * DSTATE + w * 32 + g * 4;
    __builtin_nontemporal_store(v1r, (f32x4*)(nsre + no));
    __builtin_nontemporal_store(v2r, (f32x4*)(nsre + no + 16));
    __builtin_nontemporal_store(v1i, (f32x4*)(nsim + no));
    __builtin_nontemporal_store(v2i, (f32x4*)(nsim + no + 16));
  };

  // ---- PHASE2(t): GEMM2 p-tile from pf, epilogue, out store ----
  auto PHASE2 = [&](int t) {
    const int b = t % 3;
    f32x4 a2 = {0.f,0.f,0.f,0.f};
    #pragma unroll
    for (int j = 0; j < 8; ++j) {
      const short8v pbr = *(const short8v*)&pf[0][j][lane][0];
      const short8v pbi = *(const short8v*)&pf[1][j][lane][0];
      a2 = __builtin_amdgcn_mfma_f32_16x16x32_bf16(w2r[j], pbr, a2, 0, 0, 0);
      a2 = __builtin_amdgcn_mfma_f32_16x16x32_bf16(w2i[j], pbi, a2, 0, 0, 0);
    }
    const float scl = scL[t * 16 + bl];
    const int col = h * HEAD_DIM + w * 16 + g * 4;
    const size_t o = (size_t)(blkrow + t * 16 + bl) * DIM + col;
    const unsigned short* xp =
        &xbL[b][bl][((((2 * w) + (g >> 1)) ^ (bl & 7)) << 3) + ((g & 1) << 2)];
    f32x4 ro;
    #pragma unroll
    for (int r = 0; r < 4; ++r) {
      const float xr = bf2f(xp[r]);
      ro[r] = xr * (1.0f + d4[r] * scl) + 2.0f * a2[r];
    }
    __builtin_nontemporal_store(ro, (f32x4*)(out + o));
  };

  // ---- prologue: scL (wave 0, before its stages so vm counts align) ----
  if (w == 0) stage16f(scale + blkrow + lane * 4, &scL[0]);
  STAGE(0, 0);
  STAGE(1, 1);

  for (int t = 0; t < 16; ++t) {
    if (t == 0)      asm volatile("s_waitcnt vmcnt(6)"  ::: "memory");
    else if (t == 1) asm volatile("s_waitcnt vmcnt(11)" ::: "memory");
    else if (t <= 14) asm volatile("s_waitcnt vmcnt(16)" ::: "memory");
    else             asm volatile("s_waitcnt vmcnt(10)" ::: "memory");
    BARRIER();                                       // stage(t) visible; pf free
    if (t + 2 < 16) STAGE(t + 2, (t + 2) % 3);
    __builtin_amdgcn_sched_barrier(0);               // pin vm issue order
    PHASE1(t);
    BARRIER();                                       // pf complete
    PHASE2(t);
  }
}

extern "C" void kernel_launch(void* const* d_in, const int* in_sizes, int n_in,
                              void* d_out, int out_size, void* d_ws, size_t ws_size,
                              hipStream_t stream) {
  const float* x_t      = (const float*)d_in[0];
  const float* state_re = (const float*)d_in[1];
  const float* state_im = (const float*)d_in[2];
  const float* norm_w   = (const float*)d_in[3];
  const float* A_re_log = (const float*)d_in[4];
  const float* A_im     = (const float*)d_in[5];
  const float* B_re     = (const float*)d_in[6];
  const float* B_im     = (const float*)d_in[7];
  const float* C_re     = (const float*)d_in[8];
  const float* C_im     = (const float*)d_in[9];
  const float* Dv       = (const float*)d_in[10];
  const float* log_dt   = (const float*)d_in[11];

  float* out   = (float*)d_out;
  float* ns_re = out + (size_t)BATCH * DIM;
  float* ns_im = ns_re + (size_t)BATCH * HEADS * DSTATE;

  char* ws = (char*)d_ws;
  unsigned short* w1re = (unsigned short*)ws;                       // 512 KB each
  unsigned short* w1im = w1re + 262144;
  unsigned short* w2re = w1im + 262144;
  unsigned short* w2mi = w2re + 262144;
  float* abr   = (float*)(ws + 4 * 524288);
  float* abi   = abr + 2048;
  float* scale = abi + 2048;                                        // 8192 f32
  unsigned short* xtb = (unsigned short*)(scale + 8192);            // 16.8 MB bf16 x_t

  prep<<<4096, 256, 0, stream>>>(log_dt, A_re_log, A_im, B_re, B_im, C_re, C_im,
                                 x_t, norm_w, w1re, w1im, w2re, w2mi,
                                 abr, abi, scale, xtb);
  s5_main<<<256, 512, 0, stream>>>(w1re, w1im, w2re, w2mi, abr, abi, scale, xtb,
                                   state_re, state_im, Dv, norm_w,
                                   out, ns_re, ns_im);
}